// Round 12
// baseline (296.549 us; speedup 1.0000x reference)
//
#include <hip/hip_runtime.h>
#include <hip/hip_bf16.h>
#include <math.h>

// Problem constants: B,T,D = 8,2048,1024; HID=1024, OUT=512, H=4, WIN=9
#define B_    8
#define T_    2048
#define D_    1024
#define HID_  1024
#define H_    4
#define DK_   256     // HID_/H_
#define S_ELEMS ((size_t)16384 * 1024)   // M * HID

typedef __bf16 bf16x8  __attribute__((ext_vector_type(8)));
typedef __bf16 bf16x4v __attribute__((ext_vector_type(4)));
typedef float  f32x4   __attribute__((ext_vector_type(4)));

__device__ __forceinline__ float gelu_f(float x) {
    return 0.5f * x * (1.0f + erff(x * 0.70710678118654752440f));
}

__device__ __forceinline__ void gload_lds16(const void* g, void* s) {
    __builtin_amdgcn_global_load_lds(
        (const __attribute__((address_space(1))) void*)g,
        (__attribute__((address_space(3))) void*)s, 16, 0, 0);
}

// ---------------------------------------------------------------------------
// 256x256 bf16 GEMM, v5: BK=32 for 2 blocks/CU occupancy.
// Diagnosis (r11): at BK=64/128KiB LDS, 1 block/CU -> 2 barrier-locked
// waves/SIMD; per-tile LDS-read cost (~2300 cyc/CU) ~= MFMA cost (~2480) and
// they serialize -> 38% MfmaUtil across 5 schedule variants. BK=32 halves LDS
// to 64 KiB -> 2 INDEPENDENT blocks/CU (4 waves/SIMD) whose barriers don't
// align -> cross-block read||MFMA overlap (m114 mechanism).
// Per tile: stage(t+1) 4 gload_lds -> vmcnt(4) -> barrier -> 12 ds_read_b128
// + 32 MFMA (single ks phase) -> barrier.
// LDS layout: [row][4 K-slots of 16B], swizzled: LDS slot s of row r holds
// K-slot s ^ ((r>>1)&3); read slot = lq ^ ((lr>>1)&3) (conflict-free per
// 16-lane quarter: lanes 0-7 cover all 32 banks, 8-15 repeat = 2-pass floor).
// Staging: linear LDS dest + inverse-permuted global source (rule 21).
// EPI 0: QKV fused - Cb+sel*S_ELEMS gets bf16(acc+bias[col]); sel = col>>10
// EPI 1: Cb[m,n] = bf16(acc + bias[n] + res[m,n])   (O-proj + residual, bf16)
// ---------------------------------------------------------------------------
template<int EPI>
__global__ __launch_bounds__(512) void gemm256_k(
    const __bf16* __restrict__ A, const __bf16* __restrict__ Bt,
    const float* __restrict__ bias, const float* __restrict__ res,
    float* __restrict__ Cf, __bf16* __restrict__ Cb,
    int M, int N, int K)
{
    __shared__ __bf16 lds[2][2][256 * 32];   // 64 KiB total
    const int tid = threadIdx.x;
    const int w  = tid >> 6, l = tid & 63;
    const int wm = w >> 2,  wn = w & 3;
    const int lr = l & 15, lq = l >> 4;       // lq = K-slot 0..3 (16B each)
    const int m0 = blockIdx.x * 256, n0 = blockIdx.y * 256;
    const int nt = K >> 5;                    // 32-deep K-tiles

    f32x4 acc[8][4] = {};

    // staging: 1024 chunks/panel; thread owns chunks tid and tid+512.
    // chunk i: row=i>>2, lds_slot=i&3 -> global K-slot = (i&3) ^ ((row>>1)&3)
    int srow[2], sslot[2];
    #pragma unroll
    for (int c = 0; c < 2; ++c) {
        int i = tid + c * 512;
        srow[c]  = i >> 2;
        sslot[c] = (i & 3) ^ ((srow[c] >> 1) & 3);
    }
    const int ldsu = (w * 64) * 16;           // wave-uniform dest base

    auto stageA = [&](int t) {
        char* dst = (char*)&lds[t & 1][0][0];
        #pragma unroll
        for (int c = 0; c < 2; ++c)
            gload_lds16((const char*)(A + (size_t)(m0 + srow[c]) * K + t * 32) + (sslot[c] << 4),
                        dst + ldsu + c * 512 * 16);
    };
    auto stageB = [&](int t) {
        char* dst = (char*)&lds[t & 1][1][0];
        #pragma unroll
        for (int c = 0; c < 2; ++c)
            gload_lds16((const char*)(Bt + (size_t)(n0 + srow[c]) * K + t * 32) + (sslot[c] << 4),
                        dst + ldsu + c * 512 * 16);
    };

    stageA(0);
    stageB(0);

    const int slotC = (lq ^ ((lr >> 1) & 3)) << 4;   // lane's swizzled slot (bytes)

    for (int t = 0; t < nt; ++t) {
        const int cur = t & 1;
        if (t + 1 < nt) {
            stageA(t + 1);
            stageB(t + 1);
            asm volatile("s_waitcnt vmcnt(4)" ::: "memory");   // tile t resident
        } else {
            asm volatile("s_waitcnt vmcnt(0)" ::: "memory");
        }
        __builtin_amdgcn_s_barrier();        // tile t visible to all waves
        asm volatile("" ::: "memory");

        const char* Ap = (const char*)&lds[cur][0][0];
        const char* Bp = (const char*)&lds[cur][1][0];

        bf16x8 af[8], bfr[4];
        #pragma unroll
        for (int fi = 0; fi < 8; ++fi)
            af[fi] = *(const bf16x8*)(Ap + (wm * 128 + fi * 16 + lr) * 64 + slotC);
        #pragma unroll
        for (int fj = 0; fj < 4; ++fj)
            bfr[fj] = *(const bf16x8*)(Bp + (wn * 64 + fj * 16 + lr) * 64 + slotC);
        __builtin_amdgcn_s_setprio(1);
        #pragma unroll
        for (int fi = 0; fi < 8; ++fi)
            #pragma unroll
            for (int fj = 0; fj < 4; ++fj)
                acc[fi][fj] = __builtin_amdgcn_mfma_f32_16x16x32_bf16(
                    af[fi], bfr[fj], acc[fi][fj], 0, 0, 0);
        __builtin_amdgcn_s_setprio(0);
        __builtin_amdgcn_s_barrier();        // all reads of buf[cur] done
        asm volatile("" ::: "memory");
    }

    #pragma unroll
    for (int fi = 0; fi < 8; ++fi) {
        const int row0 = m0 + wm * 128 + fi * 16 + (l >> 4) * 4;
        #pragma unroll
        for (int fj = 0; fj < 4; ++fj) {
            const int col = n0 + wn * 64 + fj * 16 + lr;
            const float bz = bias[col];
            if (EPI == 0) {
                const int sel = col >> 10, cl = col & 1023;
                __bf16* out = Cb + (size_t)sel * S_ELEMS + (size_t)row0 * 1024 + cl;
                #pragma unroll
                for (int r = 0; r < 4; ++r)
                    out[(size_t)r * 1024] = (__bf16)(acc[fi][fj][r] + bz);
            } else {
                #pragma unroll
                for (int r = 0; r < 4; ++r) {
                    size_t idx = (size_t)(row0 + r) * N + col;
                    Cb[idx] = (__bf16)(acc[fi][fj][r] + bz + res[idx]);
                }
            }
        }
    }
}

// ---------------------------------------------------------------------------
// 256x128 bf16 GEMM for the FFNs (round-10 proven). BK=64, 8 waves 2Mx4N,
// acc[8][2]; LDS 96 KiB dbuf; T2 swizzle; 6 loads/tile -> vmcnt(6).
// EPI 2: Cf[b,n,t] = gelu(acc+bias)  AND  Cb[m,n] = bf16(gelu)  (FFN1)
// EPI 3: Cf[b,n,t] = gelu(acc+bias)                             (FFN2)
// ---------------------------------------------------------------------------
template<int EPI>
__global__ __launch_bounds__(512) void gemmF_k(
    const __bf16* __restrict__ A, const __bf16* __restrict__ Bt,
    const float* __restrict__ bias,
    float* __restrict__ Cf, __bf16* __restrict__ Cb,
    int M, int N, int K)
{
    __shared__ __bf16 lds[2][384 * 64];      // A: [0,256*64) ; B: [256*64,384*64)
    const int tid = threadIdx.x;
    const int w  = tid >> 6, l = tid & 63;
    const int wm = w >> 2,  wn = w & 3;
    const int lr = l & 15, lq = l >> 4, lx = l & 7;
    const int m0 = blockIdx.x * 256, n0 = blockIdx.y * 128;
    const int nt = K >> 6;

    f32x4 acc[8][2] = {};

    int srA[4], ssA[4], srB[2], ssB[2];
    #pragma unroll
    for (int c = 0; c < 4; ++c) {
        int i = tid + c * 512;
        srA[c] = i >> 3;
        ssA[c] = (i & 7) ^ (srA[c] & 7);
    }
    #pragma unroll
    for (int c = 0; c < 2; ++c) {
        int i = tid + c * 512;
        srB[c] = i >> 3;
        ssB[c] = (i & 7) ^ (srB[c] & 7);
    }
    const int ldsu = (w * 64) * 16;

    auto stage = [&](int t) {
        char* dst = (char*)&lds[t & 1][0];
        #pragma unroll
        for (int c = 0; c < 4; ++c)
            gload_lds16((const char*)(A + (size_t)(m0 + srA[c]) * K + t * 64) + (ssA[c] << 4),
                        dst + ldsu + c * 512 * 16);
        char* dstB = dst + 256 * 64 * 2;
        #pragma unroll
        for (int c = 0; c < 2; ++c)
            gload_lds16((const char*)(Bt + (size_t)(n0 + srB[c]) * K + t * 64) + (ssB[c] << 4),
                        dstB + ldsu + c * 512 * 16);
    };

    stage(0);

    for (int t = 0; t < nt; ++t) {
        const int cur = t & 1;
        if (t + 1 < nt) {
            stage(t + 1);
            asm volatile("s_waitcnt vmcnt(6)" ::: "memory");
        } else {
            asm volatile("s_waitcnt vmcnt(0)" ::: "memory");
        }
        __builtin_amdgcn_s_barrier();
        asm volatile("" ::: "memory");

        const char* Ap = (const char*)&lds[cur][0];
        const char* Bp = Ap + 256 * 64 * 2;

        #pragma unroll
        for (int ks = 0; ks < 2; ++ks) {
            bf16x8 af[8], bfr[2];
            #pragma unroll
            for (int fi = 0; fi < 8; ++fi)
                af[fi] = *(const bf16x8*)(Ap + (wm * 128 + fi * 16 + lr) * 128
                                             + ((((ks << 2) | lq) ^ lx) << 4));
            #pragma unroll
            for (int fj = 0; fj < 2; ++fj)
                bfr[fj] = *(const bf16x8*)(Bp + (wn * 32 + fj * 16 + lr) * 128
                                              + ((((ks << 2) | lq) ^ lx) << 4));
            __builtin_amdgcn_s_setprio(1);
            #pragma unroll
            for (int fi = 0; fi < 8; ++fi)
                #pragma unroll
                for (int fj = 0; fj < 2; ++fj)
                    acc[fi][fj] = __builtin_amdgcn_mfma_f32_16x16x32_bf16(
                        af[fi], bfr[fj], acc[fi][fj], 0, 0, 0);
            __builtin_amdgcn_s_setprio(0);
        }
        __builtin_amdgcn_s_barrier();
        asm volatile("" ::: "memory");
    }

    #pragma unroll
    for (int fi = 0; fi < 8; ++fi) {
        const int row0 = m0 + wm * 128 + fi * 16 + lq * 4;
        #pragma unroll
        for (int fj = 0; fj < 2; ++fj) {
            const int col = n0 + wn * 32 + fj * 16 + lr;
            const float bz = bias[col];
            float gv[4];
            #pragma unroll
            for (int r = 0; r < 4; ++r) gv[r] = gelu_f(acc[fi][fj][r] + bz);
            const int bidx = row0 >> 11, t0 = row0 & (T_ - 1);
            float4 g4; g4.x = gv[0]; g4.y = gv[1]; g4.z = gv[2]; g4.w = gv[3];
            *(float4*)(Cf + (size_t)bidx * N * T_ + (size_t)col * T_ + t0) = g4;
            if (EPI == 2) {
                #pragma unroll
                for (int r = 0; r < 4; ++r)
                    Cb[(size_t)(row0 + r) * N + col] = (__bf16)gv[r];
            }
        }
    }
}

// ---------------------------------------------------------------------------
// Windowed attention v4 (round-11 proven): 16 threads/query, 16-dim slices,
// no LDS, no barriers; masks 1,2,4,8 shfl reduce; per-lane softmax.
// ---------------------------------------------------------------------------
__global__ __launch_bounds__(256) void attn4_k(
    const __bf16* Q, const __bf16* __restrict__ Kg, const __bf16* __restrict__ Vg,
    __bf16* O, const float* __restrict__ aw_p, const float* __restrict__ ab_p)
{
    const int tid = threadIdx.x;
    const int s  = tid & 15;
    const int ql = tid >> 4;
    const int b  = blockIdx.x >> 9;
    const int h  = (blockIdx.x >> 7) & 3;
    const int t  = ((blockIdx.x & 127) << 4) + ql;

    const size_t hbase = (size_t)b * T_ * HID_ + h * DK_ + s * 16;

    const __bf16* qp = Q + hbase + (size_t)t * HID_;
    float qf[16];
    #pragma unroll
    for (int c = 0; c < 2; ++c) {
        bf16x8 v = *(const bf16x8*)(qp + c * 8);
        #pragma unroll
        for (int e = 0; e < 8; ++e) qf[c * 8 + e] = (float)v[e];
    }

    float part[9];
    #pragma unroll
    for (int jj = 0; jj < 9; ++jj) {
        int jc = min(max(t - 4 + jj, 0), T_ - 1);
        const __bf16* kp = Kg + hbase + (size_t)jc * HID_;
        float sacc = 0.f;
        #pragma unroll
        for (int c = 0; c < 2; ++c) {
            bf16x8 kv = *(const bf16x8*)(kp + c * 8);
            #pragma unroll
            for (int e = 0; e < 8; ++e) sacc = fmaf(qf[c * 8 + e], (float)kv[e], sacc);
        }
        part[jj] = sacc;
    }

    #pragma unroll
    for (int jj = 0; jj < 9; ++jj) {
        float v = part[jj];
        v += __shfl_xor(v, 1);
        v += __shfl_xor(v, 2);
        v += __shfl_xor(v, 4);
        v += __shfl_xor(v, 8);
        part[jj] = v;
    }

    const float aw = *aw_p, ab = *ab_p;
    float sc[9], mx = -1e30f;
    #pragma unroll
    for (int jj = 0; jj < 9; ++jj) {
        int j = t - 4 + jj;
        float d = (float)(jj - 4);
        float adj = __expf(-fabsf(aw * d * d - ab));
        sc[jj] = (j >= 0 && j < T_) ? part[jj] * (1.0f / 16.0f) + adj : -1e30f;
        mx = fmaxf(mx, sc[jj]);
    }
    float wgt[9], sum = 0.f;
    #pragma unroll
    for (int jj = 0; jj < 9; ++jj) { wgt[jj] = __expf(sc[jj] - mx); sum += wgt[jj]; }
    const float inv = 1.0f / sum;

    float o[16];
    #pragma unroll
    for (int e = 0; e < 16; ++e) o[e] = 0.f;
    #pragma unroll
    for (int jj = 0; jj < 9; ++jj) {
        int jc = min(max(t - 4 + jj, 0), T_ - 1);
        const float wj = wgt[jj] * inv;
        const __bf16* vp = Vg + hbase + (size_t)jc * HID_;
        #pragma unroll
        for (int c = 0; c < 2; ++c) {
            bf16x8 vv = *(const bf16x8*)(vp + c * 8);
            #pragma unroll
            for (int e = 0; e < 8; ++e)
                o[c * 8 + e] = fmaf(wj, (float)vv[e], o[c * 8 + e]);
        }
    }

    __bf16* op = O + hbase + (size_t)t * HID_;
    #pragma unroll
    for (int c = 0; c < 2; ++c) {
        bf16x8 ov;
        #pragma unroll
        for (int e = 0; e < 8; ++e) ov[e] = (__bf16)o[c * 8 + e];
        *(bf16x8*)(op + c * 8) = ov;
    }
}

// ---------------------------------------------------------------------------
// LayerNorm over D=1024: bf16 in-place. One 256-thread block per row.
// ---------------------------------------------------------------------------
__device__ __forceinline__ float block_sum(float v, float* sm) {
    #pragma unroll
    for (int off = 32; off; off >>= 1) v += __shfl_xor(v, off);
    if ((threadIdx.x & 63) == 0) sm[threadIdx.x >> 6] = v;
    __syncthreads();
    float r = sm[0] + sm[1] + sm[2] + sm[3];
    __syncthreads();
    return r;
}

__global__ __launch_bounds__(256) void ln_k(
    __bf16* __restrict__ Yb, const float* __restrict__ g, const float* __restrict__ bta)
{
    __shared__ float sm[4];
    __bf16* y = Yb + (size_t)blockIdx.x * D_;
    bf16x4v v4 = *(const bf16x4v*)(y + threadIdx.x * 4);
    float v[4] = { (float)v4[0], (float)v4[1], (float)v4[2], (float)v4[3] };
    float mean = block_sum(v[0] + v[1] + v[2] + v[3], sm) * (1.0f / D_);
    float s2 = 0.f;
    #pragma unroll
    for (int i = 0; i < 4; ++i) { float d = v[i] - mean; s2 += d * d; }
    float rstd = rsqrtf(block_sum(s2, sm) * (1.0f / D_) + 1e-5f);
    bf16x4v o;
    #pragma unroll
    for (int i = 0; i < 4; ++i) {
        int idx = threadIdx.x * 4 + i;
        o[i] = (__bf16)((v[i] - mean) * rstd * g[idx] + bta[idx]);
    }
    *(bf16x4v*)(y + threadIdx.x * 4) = o;
}

// ---------------------------------------------------------------------------
// Fused prep (one launch): cast x, W1, W2, pack biases, 4x weight transpose.
// ---------------------------------------------------------------------------
__global__ __launch_bounds__(256) void prep_k(
    const float4* __restrict__ x4, const float4* __restrict__ W14,
    const float4* __restrict__ W24,
    const float* __restrict__ bq, const float* __restrict__ bk,
    const float* __restrict__ bv,
    const float* __restrict__ Wq, const float* __restrict__ Wk,
    const float* __restrict__ Wv, const float* __restrict__ Wo,
    bf16x4v* __restrict__ xb4, bf16x4v* __restrict__ W1b4,
    bf16x4v* __restrict__ W2b4, float* __restrict__ bqkvd,
    __bf16* __restrict__ Wqkv, __bf16* __restrict__ Wot)
{
    __shared__ float tbuf[32][33];
    const int bid = blockIdx.x, tid = threadIdx.x;
    if (bid < 16384) {
        int i = bid * 256 + tid;
        float4 v = x4[i];
        bf16x4v o; o[0] = (__bf16)v.x; o[1] = (__bf16)v.y; o[2] = (__bf16)v.z; o[3] = (__bf16)v.w;
        xb4[i] = o;
    } else if (bid < 16896) {
        int i = (bid - 16384) * 256 + tid;
        float4 v = W14[i];
        bf16x4v o; o[0] = (__bf16)v.x; o[1] = (__bf16)v.y; o[2] = (__bf16)v.z; o[3] = (__bf16)v.w;
        W1b4[i] = o;
    } else if (bid < 17152) {
        int i = (bid - 16896) * 256 + tid;
        float4 v = W24[i];
        bf16x4v o; o[0] = (__bf16)v.x; o[1] = (__bf16)v.y; o[2] = (__bf16)v.z; o[3] = (__bf16)v.w;
        W2b4[i] = o;
    } else if (bid < 17164) {
        int i = (bid - 17152) * 256 + tid;
        bqkvd[i] = (i < 1024) ? bq[i] : ((i < 2048) ? bk[i - 1024] : bv[i - 2048]);
    } else {
        int r  = bid - 17164;
        int z  = r >> 10;
        int rt = r & 1023;
        int k0 = ((rt >> 5) & 31) << 5, n0 = (rt & 31) << 5;
        const float* in = (z == 0) ? Wq : (z == 1) ? Wk : (z == 2) ? Wv : Wo;
        __bf16* out = (z < 3) ? (Wqkv + (size_t)z * 1024 * 1024) : Wot;
        int xx = tid & 31, yy = tid >> 5;
        for (int r2 = yy; r2 < 32; r2 += 8)
            tbuf[r2][xx] = in[(size_t)(k0 + r2) * 1024 + n0 + xx];
        __syncthreads();
        for (int r2 = yy; r2 < 32; r2 += 8)
            out[(size_t)(n0 + r2) * 1024 + k0 + xx] = (__bf16)tbuf[xx][r2];
    }
}

// ---------------------------------------------------------------------------
extern "C" void kernel_launch(void* const* d_in, const int* in_sizes, int n_in,
                              void* d_out, int out_size, void* d_ws, size_t ws_size,
                              hipStream_t stream) {
    const float* x    = (const float*)d_in[0];
    const float* Wq   = (const float*)d_in[2];
    const float* bq   = (const float*)d_in[3];
    const float* Wk   = (const float*)d_in[4];
    const float* bk   = (const float*)d_in[5];
    const float* Wv   = (const float*)d_in[6];
    const float* bv   = (const float*)d_in[7];
    const float* Wo   = (const float*)d_in[8];
    const float* bo   = (const float*)d_in[9];
    const float* ln_g = (const float*)d_in[10];
    const float* ln_b = (const float*)d_in[11];
    const float* W1   = (const float*)d_in[12];
    const float* b1   = (const float*)d_in[13];
    const float* W2   = (const float*)d_in[14];
    const float* b2   = (const float*)d_in[15];
    const float* adj_w = (const float*)d_in[16];
    const float* adj_b = (const float*)d_in[17];

    const int M = B_ * T_;                  // 16384
    const size_t S = S_ELEMS;               // 16.78M elems

    __bf16* Qb   = (__bf16*)d_ws;           // S  (also attention output O)
    __bf16* Kb   = Qb + S;                  // S  (dead after attn -> Yb bf16)
    __bf16* Vb   = Kb + S;                  // S
    __bf16* Yb   = Kb;                      // alias: post-residual bf16 y
    __bf16* xb   = Vb + S;                  // S
    __bf16* Wqkv = xb + S;                  // 3*1M
    __bf16* Wot  = Wqkv + 3 * 1024 * 1024;  // 1M
    __bf16* W1b  = Wot + 1024 * 1024;       // 512*1024
    __bf16* W2b  = W1b + 512 * 1024;        // 512*512
    __bf16* h1b  = W2b + 512 * 512;         // M*512
    float*  bqkvd = (float*)(h1b + (size_t)M * 512);  // 3072 f32

    float* xe = (float*)d_out;                         // [B,512,T]
    float* h1 = xe + (size_t)B_ * 512 * T_;            // [B,512,T]

    dim3 blk(256);

    // --- prep: all casts + transposes + bias pack in ONE launch ---
    prep_k<<<dim3(17164 + 4096), blk, 0, stream>>>(
        (const float4*)x, (const float4*)W1, (const float4*)W2, bq, bk, bv,
        Wq, Wk, Wv, Wo,
        (bf16x4v*)xb, (bf16x4v*)W1b, (bf16x4v*)W2b, bqkvd, Wqkv, Wot);

    // --- QKV fused projection (256^2 BK=32, 2 blocks/CU): N=3072 ---
    gemm256_k<0><<<dim3(M / 256, 3072 / 256), dim3(512), 0, stream>>>(
        xb, Wqkv, bqkvd, nullptr, nullptr, Qb, M, 3072, D_);

    // --- windowed attention v4 (O overwrites Qb): 16 thr/query ---
    attn4_k<<<dim3(B_ * H_ * (T_ / 16)), blk, 0, stream>>>(Qb, Kb, Vb, Qb, adj_w, adj_b);

    // --- O-projection + bias + residual -> Yb bf16 ---
    gemm256_k<1><<<dim3(M / 256, HID_ / 256), dim3(512), 0, stream>>>(
        Qb, Wot, bo, x, nullptr, Yb, M, D_, HID_);

    // --- LayerNorm in place (bf16) ---
    ln_k<<<dim3(M), blk, 0, stream>>>(Yb, ln_g, ln_b);

    // --- FFN1 (256x128 pipeline): gelu(W1 @ y^T) -> f32 h1 + bf16 h1b ---
    gemmF_k<2><<<dim3(M / 256, 512 / 128), dim3(512), 0, stream>>>(
        Yb, W1b, b1, h1, h1b, M, 512, D_);

    // --- FFN2 (256x128 pipeline): gelu(W2 @ h1) -> f32 xe ---
    gemmF_k<3><<<dim3(M / 256, 512 / 128), dim3(512), 0, stream>>>(
        h1b, W2b, b2, xe, nullptr, M, 512, 512);
}

// Round 14
// 259.597 us; speedup vs baseline: 1.1423x; 1.1423x over previous
//
#include <hip/hip_runtime.h>
#include <hip/hip_bf16.h>
#include <math.h>

// Problem constants: B,T,D = 8,2048,1024; HID=1024, OUT=512, H=4, WIN=9
#define B_    8
#define T_    2048
#define D_    1024
#define HID_  1024
#define H_    4
#define DK_   256     // HID_/H_
#define S_ELEMS ((size_t)16384 * 1024)   // M * HID

typedef __bf16 bf16x8  __attribute__((ext_vector_type(8)));
typedef __bf16 bf16x4v __attribute__((ext_vector_type(4)));
typedef float  f32x4   __attribute__((ext_vector_type(4)));

__device__ __forceinline__ float gelu_f(float x) {
    return 0.5f * x * (1.0f + erff(x * 0.70710678118654752440f));
}

__device__ __forceinline__ void gload_lds16(const void* g, void* s) {
    __builtin_amdgcn_global_load_lds(
        (const __attribute__((address_space(1))) void*)g,
        (__attribute__((address_space(3))) void*)s, 16, 0, 0);
}

// ---------------------------------------------------------------------------
// 256x256 bf16 GEMM (round-6 min-barrier variant — best measured, 115 us on
// QKV). BK=64, 8 waves (2Mx4N), 512 threads, T2 LDS swizzle (0 conflicts).
// stage(t+1) 8 loads -> vmcnt(8) -> barrier -> 2x{24 ds_read_b128,
// setprio(1) 32 MFMA setprio(0)} -> barrier.
// [FROZEN: 6 structural variants (3-barrier / min-barrier / 4-phase /
//  XCD-swizzle / burst-discipline / BK=32) all within ±3% at ~888 TF —
//  the plain-HIP structure ceiling for this self-derived schedule class.]
// EPI 0: QKV fused - Cb+sel*S_ELEMS gets bf16(acc+bias[col]); sel = col>>10
// EPI 1: Cb[m,n] = bf16(acc + bias[n] + (float)resb[m,n])  (O-proj+residual)
// ---------------------------------------------------------------------------
template<int EPI>
__global__ __launch_bounds__(512) void gemm256_k(
    const __bf16* __restrict__ A, const __bf16* __restrict__ Bt,
    const float* __restrict__ bias, const __bf16* __restrict__ resb,
    float* __restrict__ Cf, __bf16* __restrict__ Cb,
    int M, int N, int K)
{
    __shared__ __bf16 lds[2][2][256 * 64];
    const int tid = threadIdx.x;
    const int w  = tid >> 6, l = tid & 63;
    const int wm = w >> 2,  wn = w & 3;
    const int lr = l & 15, lq = l >> 4, lx = l & 7;
    const int m0 = blockIdx.x * 256, n0 = blockIdx.y * 256;
    const int nt = K >> 6;

    f32x4 acc[8][4] = {};

    int srow[4], sslot[4];
    #pragma unroll
    for (int c = 0; c < 4; ++c) {
        int i = tid + c * 512;
        srow[c]  = i >> 3;
        sslot[c] = (i & 7) ^ (srow[c] & 7);
    }
    const int ldsu = (w * 64) * 16;

    auto stageA = [&](int t) {
        char* dst = (char*)&lds[t & 1][0][0];
        #pragma unroll
        for (int c = 0; c < 4; ++c)
            gload_lds16((const char*)(A + (size_t)(m0 + srow[c]) * K + t * 64) + (sslot[c] << 4),
                        dst + ldsu + c * 512 * 16);
    };
    auto stageB = [&](int t) {
        char* dst = (char*)&lds[t & 1][1][0];
        #pragma unroll
        for (int c = 0; c < 4; ++c)
            gload_lds16((const char*)(Bt + (size_t)(n0 + srow[c]) * K + t * 64) + (sslot[c] << 4),
                        dst + ldsu + c * 512 * 16);
    };

    stageA(0);
    stageB(0);

    for (int t = 0; t < nt; ++t) {
        const int cur = t & 1;
        if (t + 1 < nt) {
            stageA(t + 1);
            stageB(t + 1);
            asm volatile("s_waitcnt vmcnt(8)" ::: "memory");
        } else {
            asm volatile("s_waitcnt vmcnt(0)" ::: "memory");
        }
        __builtin_amdgcn_s_barrier();        // tile t visible to all waves
        asm volatile("" ::: "memory");

        const char* Ap = (const char*)&lds[cur][0][0];
        const char* Bp = (const char*)&lds[cur][1][0];

        #pragma unroll
        for (int ks = 0; ks < 2; ++ks) {
            bf16x8 af[8], bfr[4];
            #pragma unroll
            for (int fi = 0; fi < 8; ++fi)
                af[fi] = *(const bf16x8*)(Ap + (wm * 128 + fi * 16 + lr) * 128
                                             + ((((ks << 2) | lq) ^ lx) << 4));
            #pragma unroll
            for (int fj = 0; fj < 4; ++fj)
                bfr[fj] = *(const bf16x8*)(Bp + (wn * 64 + fj * 16 + lr) * 128
                                              + ((((ks << 2) | lq) ^ lx) << 4));
            __builtin_amdgcn_s_setprio(1);
            #pragma unroll
            for (int fi = 0; fi < 8; ++fi)
                #pragma unroll
                for (int fj = 0; fj < 4; ++fj)
                    acc[fi][fj] = __builtin_amdgcn_mfma_f32_16x16x32_bf16(
                        af[fi], bfr[fj], acc[fi][fj], 0, 0, 0);
            __builtin_amdgcn_s_setprio(0);
        }
        __builtin_amdgcn_s_barrier();        // all reads of buf[cur] done
        asm volatile("" ::: "memory");
    }

    #pragma unroll
    for (int fi = 0; fi < 8; ++fi) {
        const int row0 = m0 + wm * 128 + fi * 16 + lq * 4;
        #pragma unroll
        for (int fj = 0; fj < 4; ++fj) {
            const int col = n0 + wn * 64 + fj * 16 + lr;
            const float bz = bias[col];
            if (EPI == 0) {
                const int sel = col >> 10, cl = col & 1023;
                __bf16* out = Cb + (size_t)sel * S_ELEMS + (size_t)row0 * 1024 + cl;
                #pragma unroll
                for (int r = 0; r < 4; ++r)
                    out[(size_t)r * 1024] = (__bf16)(acc[fi][fj][r] + bz);
            } else {
                #pragma unroll
                for (int r = 0; r < 4; ++r) {
                    size_t idx = (size_t)(row0 + r) * N + col;
                    Cb[idx] = (__bf16)(acc[fi][fj][r] + bz + (float)resb[idx]);
                }
            }
        }
    }
}

// ---------------------------------------------------------------------------
// 256x128 bf16 GEMM for the FFNs (round-10 proven). BK=64, 8 waves 2Mx4N,
// acc[8][2]; LDS 96 KiB dbuf; T2 swizzle; 6 loads/tile -> vmcnt(6).
// f32 transposed output stored NON-TEMPORAL (write-once, never re-read;
// note: NT store needs a true vector type -> f32x4 ext-vector, not float4).
// EPI 2: Cf[b,n,t] = gelu(acc+bias)  AND  Cb[m,n] = bf16(gelu)  (FFN1)
// EPI 3: Cf[b,n,t] = gelu(acc+bias)                             (FFN2)
// ---------------------------------------------------------------------------
template<int EPI>
__global__ __launch_bounds__(512) void gemmF_k(
    const __bf16* __restrict__ A, const __bf16* __restrict__ Bt,
    const float* __restrict__ bias,
    float* __restrict__ Cf, __bf16* __restrict__ Cb,
    int M, int N, int K)
{
    __shared__ __bf16 lds[2][384 * 64];      // A: [0,256*64) ; B: [256*64,384*64)
    const int tid = threadIdx.x;
    const int w  = tid >> 6, l = tid & 63;
    const int wm = w >> 2,  wn = w & 3;
    const int lr = l & 15, lq = l >> 4, lx = l & 7;
    const int m0 = blockIdx.x * 256, n0 = blockIdx.y * 128;
    const int nt = K >> 6;

    f32x4 acc[8][2] = {};

    int srA[4], ssA[4], srB[2], ssB[2];
    #pragma unroll
    for (int c = 0; c < 4; ++c) {
        int i = tid + c * 512;
        srA[c] = i >> 3;
        ssA[c] = (i & 7) ^ (srA[c] & 7);
    }
    #pragma unroll
    for (int c = 0; c < 2; ++c) {
        int i = tid + c * 512;
        srB[c] = i >> 3;
        ssB[c] = (i & 7) ^ (srB[c] & 7);
    }
    const int ldsu = (w * 64) * 16;

    auto stage = [&](int t) {
        char* dst = (char*)&lds[t & 1][0];
        #pragma unroll
        for (int c = 0; c < 4; ++c)
            gload_lds16((const char*)(A + (size_t)(m0 + srA[c]) * K + t * 64) + (ssA[c] << 4),
                        dst + ldsu + c * 512 * 16);
        char* dstB = dst + 256 * 64 * 2;
        #pragma unroll
        for (int c = 0; c < 2; ++c)
            gload_lds16((const char*)(Bt + (size_t)(n0 + srB[c]) * K + t * 64) + (ssB[c] << 4),
                        dstB + ldsu + c * 512 * 16);
    };

    stage(0);

    for (int t = 0; t < nt; ++t) {
        const int cur = t & 1;
        if (t + 1 < nt) {
            stage(t + 1);
            asm volatile("s_waitcnt vmcnt(6)" ::: "memory");
        } else {
            asm volatile("s_waitcnt vmcnt(0)" ::: "memory");
        }
        __builtin_amdgcn_s_barrier();
        asm volatile("" ::: "memory");

        const char* Ap = (const char*)&lds[cur][0];
        const char* Bp = Ap + 256 * 64 * 2;

        #pragma unroll
        for (int ks = 0; ks < 2; ++ks) {
            bf16x8 af[8], bfr[2];
            #pragma unroll
            for (int fi = 0; fi < 8; ++fi)
                af[fi] = *(const bf16x8*)(Ap + (wm * 128 + fi * 16 + lr) * 128
                                             + ((((ks << 2) | lq) ^ lx) << 4));
            #pragma unroll
            for (int fj = 0; fj < 2; ++fj)
                bfr[fj] = *(const bf16x8*)(Bp + (wn * 32 + fj * 16 + lr) * 128
                                              + ((((ks << 2) | lq) ^ lx) << 4));
            __builtin_amdgcn_s_setprio(1);
            #pragma unroll
            for (int fi = 0; fi < 8; ++fi)
                #pragma unroll
                for (int fj = 0; fj < 2; ++fj)
                    acc[fi][fj] = __builtin_amdgcn_mfma_f32_16x16x32_bf16(
                        af[fi], bfr[fj], acc[fi][fj], 0, 0, 0);
            __builtin_amdgcn_s_setprio(0);
        }
        __builtin_amdgcn_s_barrier();
        asm volatile("" ::: "memory");
    }

    #pragma unroll
    for (int fi = 0; fi < 8; ++fi) {
        const int row0 = m0 + wm * 128 + fi * 16 + lq * 4;
        #pragma unroll
        for (int fj = 0; fj < 2; ++fj) {
            const int col = n0 + wn * 32 + fj * 16 + lr;
            const float bz = bias[col];
            float gv[4];
            #pragma unroll
            for (int r = 0; r < 4; ++r) gv[r] = gelu_f(acc[fi][fj][r] + bz);
            const int bidx = row0 >> 11, t0 = row0 & (T_ - 1);
            f32x4 g4; g4[0] = gv[0]; g4[1] = gv[1]; g4[2] = gv[2]; g4[3] = gv[3];
            __builtin_nontemporal_store(
                g4, (f32x4*)(Cf + (size_t)bidx * N * T_ + (size_t)col * T_ + t0));
            if (EPI == 2) {
                #pragma unroll
                for (int r = 0; r < 4; ++r)
                    Cb[(size_t)(row0 + r) * N + col] = (__bf16)gv[r];
            }
        }
    }
}

// ---------------------------------------------------------------------------
// Windowed attention v4 (round-11 proven): 16 threads/query, 16-dim slices,
// no LDS, no barriers; masks 1,2,4,8 shfl reduce; per-lane softmax.
// ---------------------------------------------------------------------------
__global__ __launch_bounds__(256) void attn4_k(
    const __bf16* Q, const __bf16* __restrict__ Kg, const __bf16* __restrict__ Vg,
    __bf16* O, const float* __restrict__ aw_p, const float* __restrict__ ab_p)
{
    const int tid = threadIdx.x;
    const int s  = tid & 15;
    const int ql = tid >> 4;
    const int b  = blockIdx.x >> 9;
    const int h  = (blockIdx.x >> 7) & 3;
    const int t  = ((blockIdx.x & 127) << 4) + ql;

    const size_t hbase = (size_t)b * T_ * HID_ + h * DK_ + s * 16;

    const __bf16* qp = Q + hbase + (size_t)t * HID_;
    float qf[16];
    #pragma unroll
    for (int c = 0; c < 2; ++c) {
        bf16x8 v = *(const bf16x8*)(qp + c * 8);
        #pragma unroll
        for (int e = 0; e < 8; ++e) qf[c * 8 + e] = (float)v[e];
    }

    float part[9];
    #pragma unroll
    for (int jj = 0; jj < 9; ++jj) {
        int jc = min(max(t - 4 + jj, 0), T_ - 1);
        const __bf16* kp = Kg + hbase + (size_t)jc * HID_;
        float sacc = 0.f;
        #pragma unroll
        for (int c = 0; c < 2; ++c) {
            bf16x8 kv = *(const bf16x8*)(kp + c * 8);
            #pragma unroll
            for (int e = 0; e < 8; ++e) sacc = fmaf(qf[c * 8 + e], (float)kv[e], sacc);
        }
        part[jj] = sacc;
    }

    #pragma unroll
    for (int jj = 0; jj < 9; ++jj) {
        float v = part[jj];
        v += __shfl_xor(v, 1);
        v += __shfl_xor(v, 2);
        v += __shfl_xor(v, 4);
        v += __shfl_xor(v, 8);
        part[jj] = v;
    }

    const float aw = *aw_p, ab = *ab_p;
    float sc[9], mx = -1e30f;
    #pragma unroll
    for (int jj = 0; jj < 9; ++jj) {
        int j = t - 4 + jj;
        float d = (float)(jj - 4);
        float adj = __expf(-fabsf(aw * d * d - ab));
        sc[jj] = (j >= 0 && j < T_) ? part[jj] * (1.0f / 16.0f) + adj : -1e30f;
        mx = fmaxf(mx, sc[jj]);
    }
    float wgt[9], sum = 0.f;
    #pragma unroll
    for (int jj = 0; jj < 9; ++jj) { wgt[jj] = __expf(sc[jj] - mx); sum += wgt[jj]; }
    const float inv = 1.0f / sum;

    float o[16];
    #pragma unroll
    for (int e = 0; e < 16; ++e) o[e] = 0.f;
    #pragma unroll
    for (int jj = 0; jj < 9; ++jj) {
        int jc = min(max(t - 4 + jj, 0), T_ - 1);
        const float wj = wgt[jj] * inv;
        const __bf16* vp = Vg + hbase + (size_t)jc * HID_;
        #pragma unroll
        for (int c = 0; c < 2; ++c) {
            bf16x8 vv = *(const bf16x8*)(vp + c * 8);
            #pragma unroll
            for (int e = 0; e < 8; ++e)
                o[c * 8 + e] = fmaf(wj, (float)vv[e], o[c * 8 + e]);
        }
    }

    __bf16* op = O + hbase + (size_t)t * HID_;
    #pragma unroll
    for (int c = 0; c < 2; ++c) {
        bf16x8 ov;
        #pragma unroll
        for (int e = 0; e < 8; ++e) ov[e] = (__bf16)o[c * 8 + e];
        *(bf16x8*)(op + c * 8) = ov;
    }
}

// ---------------------------------------------------------------------------
// LayerNorm over D=1024: bf16 in-place. One 256-thread block per row.
// ---------------------------------------------------------------------------
__device__ __forceinline__ float block_sum(float v, float* sm) {
    #pragma unroll
    for (int off = 32; off; off >>= 1) v += __shfl_xor(v, off);
    if ((threadIdx.x & 63) == 0) sm[threadIdx.x >> 6] = v;
    __syncthreads();
    float r = sm[0] + sm[1] + sm[2] + sm[3];
    __syncthreads();
    return r;
}

__global__ __launch_bounds__(256) void ln_k(
    __bf16* __restrict__ Yb, const float* __restrict__ g, const float* __restrict__ bta)
{
    __shared__ float sm[4];
    __bf16* y = Yb + (size_t)blockIdx.x * D_;
    bf16x4v v4 = *(const bf16x4v*)(y + threadIdx.x * 4);
    float v[4] = { (float)v4[0], (float)v4[1], (float)v4[2], (float)v4[3] };
    float mean = block_sum(v[0] + v[1] + v[2] + v[3], sm) * (1.0f / D_);
    float s2 = 0.f;
    #pragma unroll
    for (int i = 0; i < 4; ++i) { float d = v[i] - mean; s2 += d * d; }
    float rstd = rsqrtf(block_sum(s2, sm) * (1.0f / D_) + 1e-5f);
    bf16x4v o;
    #pragma unroll
    for (int i = 0; i < 4; ++i) {
        int idx = threadIdx.x * 4 + i;
        o[i] = (__bf16)((v[i] - mean) * rstd * g[idx] + bta[idx]);
    }
    *(bf16x4v*)(y + threadIdx.x * 4) = o;
}

// ---------------------------------------------------------------------------
// Fused prep (one launch): cast x, W1, W2, pack biases, 4x weight transpose.
// ---------------------------------------------------------------------------
__global__ __launch_bounds__(256) void prep_k(
    const float4* __restrict__ x4, const float4* __restrict__ W14,
    const float4* __restrict__ W24,
    const float* __restrict__ bq, const float* __restrict__ bk,
    const float* __restrict__ bv,
    const float* __restrict__ Wq, const float* __restrict__ Wk,
    const float* __restrict__ Wv, const float* __restrict__ Wo,
    bf16x4v* __restrict__ xb4, bf16x4v* __restrict__ W1b4,
    bf16x4v* __restrict__ W2b4, float* __restrict__ bqkvd,
    __bf16* __restrict__ Wqkv, __bf16* __restrict__ Wot)
{
    __shared__ float tbuf[32][33];
    const int bid = blockIdx.x, tid = threadIdx.x;
    if (bid < 16384) {
        int i = bid * 256 + tid;
        float4 v = x4[i];
        bf16x4v o; o[0] = (__bf16)v.x; o[1] = (__bf16)v.y; o[2] = (__bf16)v.z; o[3] = (__bf16)v.w;
        xb4[i] = o;
    } else if (bid < 16896) {
        int i = (bid - 16384) * 256 + tid;
        float4 v = W14[i];
        bf16x4v o; o[0] = (__bf16)v.x; o[1] = (__bf16)v.y; o[2] = (__bf16)v.z; o[3] = (__bf16)v.w;
        W1b4[i] = o;
    } else if (bid < 17152) {
        int i = (bid - 16896) * 256 + tid;
        float4 v = W24[i];
        bf16x4v o; o[0] = (__bf16)v.x; o[1] = (__bf16)v.y; o[2] = (__bf16)v.z; o[3] = (__bf16)v.w;
        W2b4[i] = o;
    } else if (bid < 17164) {
        int i = (bid - 17152) * 256 + tid;
        bqkvd[i] = (i < 1024) ? bq[i] : ((i < 2048) ? bk[i - 1024] : bv[i - 2048]);
    } else {
        int r  = bid - 17164;
        int z  = r >> 10;
        int rt = r & 1023;
        int k0 = ((rt >> 5) & 31) << 5, n0 = (rt & 31) << 5;
        const float* in = (z == 0) ? Wq : (z == 1) ? Wk : (z == 2) ? Wv : Wo;
        __bf16* out = (z < 3) ? (Wqkv + (size_t)z * 1024 * 1024) : Wot;
        int xx = tid & 31, yy = tid >> 5;
        for (int r2 = yy; r2 < 32; r2 += 8)
            tbuf[r2][xx] = in[(size_t)(k0 + r2) * 1024 + n0 + xx];
        __syncthreads();
        for (int r2 = yy; r2 < 32; r2 += 8)
            out[(size_t)(n0 + r2) * 1024 + k0 + xx] = (__bf16)tbuf[xx][r2];
    }
}

// ---------------------------------------------------------------------------
extern "C" void kernel_launch(void* const* d_in, const int* in_sizes, int n_in,
                              void* d_out, int out_size, void* d_ws, size_t ws_size,
                              hipStream_t stream) {
    const float* x    = (const float*)d_in[0];
    const float* Wq   = (const float*)d_in[2];
    const float* bq   = (const float*)d_in[3];
    const float* Wk   = (const float*)d_in[4];
    const float* bk   = (const float*)d_in[5];
    const float* Wv   = (const float*)d_in[6];
    const float* bv   = (const float*)d_in[7];
    const float* Wo   = (const float*)d_in[8];
    const float* bo   = (const float*)d_in[9];
    const float* ln_g = (const float*)d_in[10];
    const float* ln_b = (const float*)d_in[11];
    const float* W1   = (const float*)d_in[12];
    const float* b1   = (const float*)d_in[13];
    const float* W2   = (const float*)d_in[14];
    const float* b2   = (const float*)d_in[15];
    const float* adj_w = (const float*)d_in[16];
    const float* adj_b = (const float*)d_in[17];

    const int M = B_ * T_;                  // 16384
    const size_t S = S_ELEMS;               // 16.78M elems

    __bf16* Qb   = (__bf16*)d_ws;           // S  (also attention output O)
    __bf16* Kb   = Qb + S;                  // S  (dead after attn -> Yb bf16)
    __bf16* Vb   = Kb + S;                  // S
    __bf16* Yb   = Kb;                      // alias: post-residual bf16 y
    __bf16* xb   = Vb + S;                  // S
    __bf16* Wqkv = xb + S;                  // 3*1M
    __bf16* Wot  = Wqkv + 3 * 1024 * 1024;  // 1M
    __bf16* W1b  = Wot + 1024 * 1024;       // 512*1024
    __bf16* W2b  = W1b + 512 * 1024;        // 512*512
    __bf16* h1b  = W2b + 512 * 512;         // M*512
    float*  bqkvd = (float*)(h1b + (size_t)M * 512);  // 3072 f32

    float* xe = (float*)d_out;                         // [B,512,T]
    float* h1 = xe + (size_t)B_ * 512 * T_;            // [B,512,T]

    dim3 blk(256);

    // --- prep: all casts + transposes + bias pack in ONE launch ---
    prep_k<<<dim3(17164 + 4096), blk, 0, stream>>>(
        (const float4*)x, (const float4*)W1, (const float4*)W2, bq, bk, bv,
        Wq, Wk, Wv, Wo,
        (bf16x4v*)xb, (bf16x4v*)W1b, (bf16x4v*)W2b, bqkvd, Wqkv, Wot);

    // --- QKV fused projection (256^2 pipelined MFMA): N=3072 ---
    gemm256_k<0><<<dim3(M / 256, 3072 / 256), dim3(512), 0, stream>>>(
        xb, Wqkv, bqkvd, nullptr, nullptr, Qb, M, 3072, D_);

    // --- windowed attention v4 (O overwrites Qb): 16 thr/query ---
    attn4_k<<<dim3(B_ * H_ * (T_ / 16)), blk, 0, stream>>>(Qb, Kb, Vb, Qb, adj_w, adj_b);

    // --- O-projection + bias + residual(bf16 xb) -> Yb bf16 ---
    gemm256_k<1><<<dim3(M / 256, HID_ / 256), dim3(512), 0, stream>>>(
        Qb, Wot, bo, xb, nullptr, Yb, M, D_, HID_);

    // --- LayerNorm in place (bf16) ---
    ln_k<<<dim3(M), blk, 0, stream>>>(Yb, ln_g, ln_b);

    // --- FFN1 (256x128 pipeline): gelu(W1 @ y^T) -> f32 h1 (NT) + bf16 h1b ---
    gemmF_k<2><<<dim3(M / 256, 512 / 128), dim3(512), 0, stream>>>(
        Yb, W1b, b1, h1, h1b, M, 512, D_);

    // --- FFN2 (256x128 pipeline): gelu(W2 @ h1) -> f32 xe (NT) ---
    gemmF_k<3><<<dim3(M / 256, 512 / 128), dim3(512), 0, stream>>>(
        h1b, W2b, b2, xe, nullptr, M, 512, 512);
}